// Round 4
// baseline (329.354 us; speedup 1.0000x reference)
//
#include <hip/hip_runtime.h>
#include <math.h>

#define NB 32
#define CIN 32
#define DIM 32
#define KK 5
#define VALID 17
#define CVOL (VALID*VALID*VALID)   // 4913
#define RS 40                      // slab row stride (words) = 10 quads
#define PLANES 11
#define ROWSL 43                   // covers sr = 8*h4 + j up to 42 (h4=4 garbage rows read as zeros)
#define SLABW (PLANES*ROWSL*RS)    // 18920 words = 75680 B -> 2 blocks/CU

// ws layout (floats): [0,4000) = w_eff ; [4000] = B ; [4096, ...) = C partials [nsplit][32][4913]

__global__ __launch_bounds__(256) void prep_kernel(const float* __restrict__ weight,
                                                   const float* __restrict__ bias,
                                                   float* __restrict__ ws) {
    int idx = blockIdx.x * 256 + threadIdx.x;
    if (idx < 4000) {
        float s = 0.f;
        #pragma unroll 8
        for (int co = 0; co < 64; ++co) s += weight[co * 4000 + idx];
        ws[idx] = s;
    }
    if (idx == 0) {
        float b = 0.f;
        for (int i = 0; i < 64; ++i) b += bias[i];
        ws[4000] = b;
    }
}

// Block = (split s, n, d-quad q). 192 threads; 180 compute-active:
// dq = tid/45 in [0,4), h4 = (tid%45)/9, wq0 = tid%9.
// Thread computes outputs d = 4q+dq, h = 4*h4..4*h4+3, w = 2*wq, 2*wq+1
// where wq = (wq0+h4+dq)%9 (rotation -> near-uniform bank-quad spread).
// Slab: [plane 11][row 43][RS 40]; plane p = input id 2*d0-2+p; row = ih+2; col = iw+2.
__global__ __launch_bounds__(192) void conv_kernel(const float* __restrict__ x,
                                                   const float* __restrict__ weff,
                                                   float* __restrict__ C,
                                                   int cpS) {
    __shared__ __align__(16) float slab[PLANES][ROWSL][RS];
    const int b = blockIdx.x;
    const int s = b / (NB * 5);
    const int rem = b - s * (NB * 5);
    const int n = rem / 5;
    const int q = rem - n * 5;
    const int d0 = 4 * q;
    const int tid = threadIdx.x;

    const int dq  = tid / 45;
    const int r45 = tid - dq * 45;
    const int h4  = r45 / 9;
    const int wq0 = r45 - h4 * 9;
    const int wq  = (wq0 + h4 + dq) % 9;
    const int d   = d0 + dq;
    const bool active = (dq < 4) && (d < VALID);
    const int h0 = 4 * h4;

    // zero whole slab once (pads + OOB planes/rows stay zero; valid region rewritten per cin)
    float4* s4 = (float4*)slab;
    for (int t = tid; t < SLABW / 4; t += 192) s4[t] = make_float4(0.f, 0.f, 0.f, 0.f);

    const int cin0 = s * cpS;
    float4 pf[15];

    // prefetch first cin
    {
        const int cin = cin0;
        #pragma unroll
        for (int i = 0; i < 15; ++i) {
            int g = tid + 192 * i;
            int p  = g >> 8;
            int rr = (g >> 3) & 31;
            int c4 = g & 7;
            int id = 2 * d0 - 2 + p;
            bool ok = (g < 2816) && (id >= 0) && (id < DIM);
            pf[i] = ok ? *(const float4*)&x[((((size_t)n * CIN + cin) * DIM + id) * DIM + rr) * DIM + 4 * c4]
                       : make_float4(0.f, 0.f, 0.f, 0.f);
        }
    }
    __syncthreads();   // zero-fill complete

    float acc0[4] = {0.f, 0.f, 0.f, 0.f};
    float acc1[4] = {0.f, 0.f, 0.f, 0.f};

    for (int ci = 0; ci < cpS; ++ci) {
        const int cin = cin0 + ci;

        // write prefetched registers to slab
        #pragma unroll
        for (int i = 0; i < 15; ++i) {
            int g = tid + 192 * i;
            if (g < 2816) {
                int p  = g >> 8;
                int rr = (g >> 3) & 31;
                int c4 = g & 7;
                float* dst = &slab[p][rr + 2][2 + 4 * c4];
                *(float2*)dst       = make_float2(pf[i].x, pf[i].y);
                *(float2*)(dst + 2) = make_float2(pf[i].z, pf[i].w);
            }
        }
        __syncthreads();

        // issue next cin's global loads; they complete under the compute phase
        if (ci + 1 < cpS) {
            const int cinN = cin + 1;
            #pragma unroll
            for (int i = 0; i < 15; ++i) {
                int g = tid + 192 * i;
                int p  = g >> 8;
                int rr = (g >> 3) & 31;
                int c4 = g & 7;
                int id = 2 * d0 - 2 + p;
                bool ok = (g < 2816) && (id >= 0) && (id < DIM);
                pf[i] = ok ? *(const float4*)&x[((((size_t)n * CIN + cinN) * DIM + id) * DIM + rr) * DIM + 4 * c4]
                           : make_float4(0.f, 0.f, 0.f, 0.f);
            }
        }

        if (active) {
            const float* wb = weff + cin * 125;
            #pragma unroll
            for (int kd = 0; kd < KK; ++kd) {
                const float* plane = &slab[2 * dq + kd][0][0];
                #pragma unroll
                for (int j = 0; j < 11; ++j) {
                    const int sr = 8 * h4 + j;
                    const float4* rowp = (const float4*)(plane + sr * RS);
                    float4 va = rowp[wq];
                    float4 vb = rowp[wq + 1];
                    #pragma unroll
                    for (int hh = 0; hh < 4; ++hh) {
                        const int kh = j - 2 * hh;
                        if (kh >= 0 && kh < KK) {
                            const float w0 = wb[(kd * 5 + kh) * 5 + 0];
                            const float w1 = wb[(kd * 5 + kh) * 5 + 1];
                            const float w2 = wb[(kd * 5 + kh) * 5 + 2];
                            const float w3 = wb[(kd * 5 + kh) * 5 + 3];
                            const float w4 = wb[(kd * 5 + kh) * 5 + 4];
                            acc0[hh] = fmaf(w0, va.x, acc0[hh]);
                            acc1[hh] = fmaf(w0, va.z, acc1[hh]);
                            acc0[hh] = fmaf(w1, va.y, acc0[hh]);
                            acc1[hh] = fmaf(w1, va.w, acc1[hh]);
                            acc0[hh] = fmaf(w2, va.z, acc0[hh]);
                            acc1[hh] = fmaf(w2, vb.x, acc1[hh]);
                            acc0[hh] = fmaf(w3, va.w, acc0[hh]);
                            acc1[hh] = fmaf(w3, vb.y, acc1[hh]);
                            acc0[hh] = fmaf(w4, vb.x, acc0[hh]);
                            acc1[hh] = fmaf(w4, vb.z, acc1[hh]);
                        }
                    }
                }
            }
        }
        __syncthreads();
    }

    if (active) {
        float* Cb = C + ((size_t)s * NB + n) * CVOL + (size_t)d * (VALID * VALID);
        #pragma unroll
        for (int hh = 0; hh < 4; ++hh) {
            int h = h0 + hh;
            if (h < VALID) {
                float* Cn = Cb + h * VALID;
                int w0 = 2 * wq;
                Cn[w0] = acc0[hh];
                if (w0 + 1 < VALID) Cn[w0 + 1] = acc1[hh];
            }
        }
    }
}

// One thread per output element [32][10][10][10]; sums nsplit partial C buffers.
__global__ __launch_bounds__(256) void pool_kernel(const float* __restrict__ C,
                                                   const float* __restrict__ wsB,
                                                   float* __restrict__ out,
                                                   int nsplit) {
    int idx = blockIdx.x * 256 + threadIdx.x;
    if (idx >= 32000) return;
    int n = idx / 1000;
    int r = idx - n * 1000;
    int i = r / 100;
    int r2 = r - i * 100;
    int j = r2 / 10;
    int k = r2 - j * 10;

    float B = wsB[0];
    float result;
    if (i < 3 && j < 3 && k < 3) {
        result = 0.f;
        for (int a = 3*i; a < 3*i + 3; ++a)
            for (int bb = 3*j; bb < 3*j + 3; ++bb)
                for (int c = 3*k; c < 3*k + 3; ++c) {
                    float m = -INFINITY;
                    #pragma unroll
                    for (int dd = 0; dd < 2; ++dd)
                        #pragma unroll
                        for (int dh = 0; dh < 2; ++dh)
                            #pragma unroll
                            for (int dw = 0; dw < 2; ++dw) {
                                int dz = 2*a + dd, hz = 2*bb + dh, wz = 2*c + dw;
                                float v;
                                if (dz < VALID && hz < VALID && wz < VALID) {
                                    size_t o = (size_t)n * CVOL + ((size_t)dz * VALID + hz) * VALID + wz;
                                    float sum = 0.f;
                                    for (int ss = 0; ss < nsplit; ++ss)
                                        sum += C[(size_t)ss * NB * CVOL + o];
                                    v = sum + B;
                                } else {
                                    v = B;
                                }
                                m = fmaxf(m, v);
                            }
                    result += m;
                }
    } else {
        result = 27.f * B;
    }
    out[idx] = result;
}

extern "C" void kernel_launch(void* const* d_in, const int* in_sizes, int n_in,
                              void* d_out, int out_size, void* d_ws, size_t ws_size,
                              hipStream_t stream) {
    const float* x      = (const float*)d_in[0];
    const float* weight = (const float*)d_in[1];
    const float* bias   = (const float*)d_in[2];
    float* out = (float*)d_out;
    float* ws  = (float*)d_ws;
    float* weff = ws;
    float* wsB  = ws + 4000;
    float* C    = ws + 4096;

    // pick cin-split by available workspace
    int nsplit = 1;
    if      (ws_size >= (size_t)(4096 + 8 * NB * CVOL) * 4) nsplit = 8;
    else if (ws_size >= (size_t)(4096 + 4 * NB * CVOL) * 4) nsplit = 4;
    else if (ws_size >= (size_t)(4096 + 2 * NB * CVOL) * 4) nsplit = 2;
    int cpS = CIN / nsplit;

    prep_kernel<<<dim3(16), dim3(256), 0, stream>>>(weight, bias, ws);
    conv_kernel<<<dim3(nsplit * NB * 5), dim3(192), 0, stream>>>(x, weff, C, cpS);
    pool_kernel<<<dim3(125), dim3(256), 0, stream>>>(C, wsB, out, nsplit);
}